// Round 6
// baseline (47328.470 us; speedup 1.0000x reference)
//
#include <hip/hip_runtime.h>
#include <stdint.h>

// ---------------------------------------------------------------------------
// StabilizedNeuralODE v7: direct L2->VGPR weight stream (no LDS round-trip).
//
// v4-v6 pushed weights through global_load_lds -> LDS ring -> ds_read ->
// VGPR with a per-iteration lgkmcnt(0) drain; plateaued at ~34-37 ms and
// v6's "VGPR-resident" w1/A silently rematerialized (VGPR_Count stayed 128).
// v7 streams weights straight to registers:
//  - Pre-permuted stream (consumption order, per wave): iter m (of 20/stage)
//    consumes bytes m*4096..+4096; the stream wraps exactly once per stage,
//    so all source offsets are COMPILE-TIME constants.
//  - 4 static register buffers bb[4][4] (bf16x8 each), all indices constant
//    after full unroll -> pure VGPRs. Loads for iter m+3 are issued at the
//    top of iter m (distance 3 ~= 600+ cyc > L2 latency), pinned ahead of
//    the MFMA cluster by sched_barrier(0). RAW vmcnt waits are left to the
//    compiler (tight counted waits on register destinations).
//  - w1 (16 frags) + A (4 frags) VGPR-resident, PINNED with asm "+v" so the
//    compiler cannot sink the loads back into the loop.
//  - LDS holds activations only (h1/h2/y frags + tables, 43 KB). Barriers:
//    3 per stage, raw s_barrier + lgkmcnt(0); vmcnt never drained in-loop.
//
// Structure: 32 WGs x 512 threads (8 waves, 2/SIMD); WG owns 16 batch rows.
// Stream per wave per stage: 80 KB (w2 64 KB + w3 16 KB); phase A and A@y
// use the resident fragments.
//
// MFMA 16x16x32_bf16 (verified): A-frag A[m=l16][k=quad*8+j],
// B-frag B[n=l16][k=quad*8+j], C/D n=l16, m=quad*4+reg.
// ---------------------------------------------------------------------------

#define Dd 128
#define Ww 512
#define Tt 512
#define NSTEP 511
#define NWG 32
#define NTHR 512

// workspace (ushort element offsets)
#define WSTR_W 40960            // stream: 40 groups x 1024 ush per wave
#define WSTAT_BASE 327680       // 8 * WSTR_W
#define WSTAT_W 10240           // static: 10 group-pairs per wave (w1 + A)
#define WS_TOT 409600           // 819,200 bytes

// LDS byte offsets (activations only)
#define H1F 0                   // 16 x 512 bf16, fragment order (16 KB)
#define H2F 16384
#define Y0F 32768               // 16 x 128 bf16 frags (4 KB)
#define Y1F 36864
#define ATF 40960               // 6 x 8 f32 RK rows (192 B)
#define DTF 41152               // 511 f32 dt values
#define SMEMB 43200

typedef __attribute__((ext_vector_type(8))) __bf16 bf16x8;
typedef __attribute__((ext_vector_type(4))) float f32x4;

__device__ __forceinline__ unsigned short f2b(float f) {
  union { float f; unsigned int u; } v; v.f = f;
  return (unsigned short)((v.u + 0x7fffu + ((v.u >> 16) & 1u)) >> 16);
}
__device__ __forceinline__ float fast_tanh(float x) {
  x = fminf(fmaxf(x, -15.f), 15.f);
  float e = __expf(2.f * x);
  return (e - 1.f) / (e + 1.f);
}
// frag byte address of element (m=batch row 0..15, n=feature col):
// tile n>>5 (1 KB), lane ((n>>3)&3)*16+m (16 B), elem n&7.
__device__ __forceinline__ int fragaddr(int m, int n) {
  return ((n >> 5) << 10) + ((((n >> 3) & 3) * 16 + m) << 4) + ((n & 7) << 1);
}

// RK coefficients: rows 0..4 = A(s+1,*) zero-padded to 8, row 5 = B.
__device__ const float RKC[48] = {
  0.161f, 0.f, 0.f, 0.f, 0.f, 0.f, 0.f, 0.f,
  -0.008480655492356989f, 0.335480655492357f, 0.f, 0.f, 0.f, 0.f, 0.f, 0.f,
  2.8971530571054935f, -6.359448489975075f, 4.3622954328695815f, 0.f, 0.f, 0.f, 0.f, 0.f,
  5.325864828439257f, -11.748883564062828f, 7.4955393428898365f,
  -0.09249506636175525f, 0.f, 0.f, 0.f, 0.f,
  5.86145544294642f, -12.92096931784711f, 8.159367898576159f,
  -0.071584973281401f, -0.028269050394068383f, 0.f, 0.f, 0.f,
  0.09646076681806523f, 0.01f, 0.4798896504144996f, 1.379008574103742f,
  -3.290069515436081f, 2.324710524099774f, 0.f, 0.f
};

// stream source byte offset for logical iter mm (20 iters/stage, exact wrap)
#define SRCB(mm) ((((mm) % 20)) * 4096)
// load one 4 KB iteration group into register buffer bi (4 x dwordx4/lane)
#define LDGRP(bi, mm) do { \
    bb[bi][0] = *(const bf16x8*)(gsb + SRCB(mm)); \
    bb[bi][1] = *(const bf16x8*)(gsb + SRCB(mm) + 1024); \
    bb[bi][2] = *(const bf16x8*)(gsb + SRCB(mm) + 2048); \
    bb[bi][3] = *(const bf16x8*)(gsb + SRCB(mm) + 3072); \
  } while (0)

// barrier that does NOT drain vmcnt
#define LBAR() do { asm volatile("s_waitcnt lgkmcnt(0)" ::: "memory"); \
                    __builtin_amdgcn_s_barrier(); } while (0)

#define MFMA(a, b, c) __builtin_amdgcn_mfma_f32_16x16x32_bf16((a), (b), (c), 0, 0, 0)
#define CPK(kd) do { kd[0]=kk[0]; kd[1]=kk[1]; kd[2]=kk[2]; kd[3]=kk[3]; } while (0)

// one-time permute+convert into workspace (stream + static, frag order)
__global__ void prep_kernel(const float* __restrict__ w1,
                            const float* __restrict__ w2,
                            const float* __restrict__ w3,
                            const float* __restrict__ Am,
                            unsigned short* __restrict__ wsb) {
  for (int i = blockIdx.x * blockDim.x + threadIdx.x; i < WS_TOT;
       i += gridDim.x * blockDim.x) {
    float v;
    if (i < WSTAT_BASE) {                       // stream region
      const int w = i / WSTR_W, r = i % WSTR_W;
      const int g = r >> 10, tile = (r >> 9) & 1;
      const int L = (r >> 3) & 63, j = r & 7;
      const int l16 = L & 15, q = L >> 4;
      if (g < 32) {
        const int nt = (g & 1) * 2 + tile, ks = g >> 1;
        v = w2[(w * 64 + nt * 16 + l16) * Ww + ks * 32 + q * 8 + j];
      } else {
        const int kcol = 2 * (g - 32) + tile;
        v = w3[(w * 16 + l16) * Ww + kcol * 32 + q * 8 + j];
      }
    } else {                                    // static region (w1, A)
      const int ii = i - WSTAT_BASE;
      const int w = ii / WSTAT_W, r = ii % WSTAT_W;
      const int idx = r >> 10, tile = (r >> 9) & 1;
      const int L = (r >> 3) & 63, j = r & 7;
      const int l16 = L & 15, q = L >> 4;
      if (idx < 8) {
        const int ks = idx >> 1, nt = (idx & 1) * 2 + tile;
        v = w1[(w * 64 + nt * 16 + l16) * Dd + ks * 32 + q * 8 + j];
      } else {
        const int kcol = 2 * (idx - 8) + tile;
        v = Am[(w * 16 + l16) * Dd + kcol * 32 + q * 8 + j];
      }
    }
    wsb[i] = f2b(v);
  }
}

__global__ void __launch_bounds__(NTHR, 1)
ode_kernel(const float* __restrict__ ts,
           const float* __restrict__ yi,
           const float* __restrict__ b1,
           const float* __restrict__ b2,
           const float* __restrict__ b3,
           float* __restrict__ out,
           const unsigned short* __restrict__ wsb)
{
  extern __shared__ char smem_c[];

  const int tid  = threadIdx.x;
  const int wid  = tid >> 6;
  const int lane = tid & 63;
  const int l16  = lane & 15;
  const int quad = lane >> 4;
  const int lob  = lane << 4;          // lane*16 bytes (LDS frag reads)
  const int b0   = blockIdx.x * 16;

  char* h1f = smem_c + H1F;
  char* h2f = smem_c + H2F;

  // per-wave stream source base (lane-linear within each 1 KB tile)
  const char* gsb = (const char*)(wsb + wid * WSTR_W) + (lane << 4);
  const unsigned short* wstat = wsb + WSTAT_BASE + wid * WSTAT_W;

  // ---- VGPR-resident w1 / A fragments, PINNED so they cannot be sunk ----
  bf16x8 w1f[4][4];   // [ks][nt]
  #pragma unroll
  for (int ks = 0; ks < 4; ++ks)
    #pragma unroll
    for (int nt = 0; nt < 4; ++nt)
      w1f[ks][nt] = *(const bf16x8*)(wstat + (2*ks + (nt>>1)) * 1024 +
                                     (nt & 1) * 512 + (lane << 3));
  bf16x8 Af[4];       // [kcol]
  #pragma unroll
  for (int kc = 0; kc < 4; ++kc)
    Af[kc] = *(const bf16x8*)(wstat + 8192 + (kc>>1) * 1024 +
                              (kc & 1) * 512 + (lane << 3));
  #pragma unroll
  for (int ks = 0; ks < 4; ++ks)
    #pragma unroll
    for (int nt = 0; nt < 4; ++nt)
      asm volatile("" : "+v"(w1f[ks][nt]));
  #pragma unroll
  for (int kc = 0; kc < 4; ++kc)
    asm volatile("" : "+v"(Af[kc]));

  // ---- one-time staging: RK table + dt into LDS; biases into regs ----
  if (tid < 48) *(float*)(smem_c + ATF + (tid << 2)) = RKC[tid];
  for (int i = tid; i < NSTEP; i += NTHR)
    *(float*)(smem_c + DTF + (i << 2)) = ts[i + 1] - ts[i];

  float b1v[4], b2v[4];
  #pragma unroll
  for (int nt = 0; nt < 4; ++nt) {
    b1v[nt] = b1[(wid << 6) + (nt << 4) + l16];
    b2v[nt] = b2[(wid << 6) + (nt << 4) + l16];
  }
  const float b3v = b3[(wid << 4) + l16];

  // h-frag write bases: n = wid*64+nt*16+l16, m = quad*4 (+r = r*16 B)
  int hwaddr[4];
  #pragma unroll
  for (int nt = 0; nt < 4; ++nt)
    hwaddr[nt] = fragaddr(quad << 2, (wid << 6) + (nt << 4) + l16);
  const int nC = (wid << 4) + l16;          // phase C/D column
  const int ydst = fragaddr(quad << 2, nC); // y-frag write base

  // ---- y0: 4 fp32 regs (rows quad*4+r, col nC), Y0F frags, out[t=0] ----
  float y[4];
  #pragma unroll
  for (int r = 0; r < 4; ++r) {
    y[r] = yi[(size_t)(b0 + (quad << 2) + r) * Dd + nC];
    *(unsigned short*)(smem_c + Y0F + ydst + (r << 4)) = f2b(y[r]);
    out[(size_t)(b0 + (quad << 2) + r) * (Tt * Dd) + nC] = y[r];
  }

  float k0[4] = {0,0,0,0}, k1[4] = {0,0,0,0}, k2[4] = {0,0,0,0},
        k3[4] = {0,0,0,0}, k4[4] = {0,0,0,0}, k5[4] = {0,0,0,0};

  __syncthreads();   // init visible

  // stream register buffers; prologue = iters 0..2 in flight
  bf16x8 bb[4][4];
  LDGRP(0, 0); LDGRP(1, 1); LDGRP(2, 2);

  #pragma unroll 1
  for (int t = 0; t < NSTEP; ++t) {
    const float hdt = *(const float*)(smem_c + DTF + (t << 2));

    #pragma unroll 1
    for (int s = 0; s < 6; ++s) {
      const char* ybr = smem_c + ((s & 1) ? Y1F : Y0F);
      char*       ybw = smem_c + ((s & 1) ? Y0F : Y1F);

      LBAR();   // y(parity) ready; h buffers free

      // ---- phase A: h1 = tanh(a @ w1.T + b1); w1 resident ---------------
      {
        f32x4 accA[4];
        #pragma unroll
        for (int nt = 0; nt < 4; ++nt) { f32x4 z = {0.f,0.f,0.f,0.f}; accA[nt] = z; }
        #pragma unroll
        for (int ks = 0; ks < 4; ++ks) {
          bf16x8 af = *(const bf16x8*)(ybr + (ks << 10) + lob);
          #pragma unroll
          for (int nt = 0; nt < 4; ++nt)
            accA[nt] = MFMA(af, w1f[ks][nt], accA[nt]);
        }
        #pragma unroll
        for (int nt = 0; nt < 4; ++nt)
          #pragma unroll
          for (int r = 0; r < 4; ++r)
            *(unsigned short*)(h1f + hwaddr[nt] + (r << 4)) =
                f2b(fast_tanh(accA[nt][r] + b1v[nt]));
      }
      LBAR();   // h1 ready

      // ---- phase B: h2 = tanh(h1 @ w2.T + b2); stream iters 0..15 -------
      {
        f32x4 accB[4];
        #pragma unroll
        for (int nt = 0; nt < 4; ++nt) { f32x4 z = {0.f,0.f,0.f,0.f}; accB[nt] = z; }
        #pragma unroll
        for (int m = 0; m < 16; ++m) {
          LDGRP((m + 3) & 3, m + 3);              // issue for iter m+3
          __builtin_amdgcn_sched_barrier(0);      // pin loads ahead of MFMAs
          bf16x8 af = *(const bf16x8*)(h1f + (m << 10) + lob);
          #pragma unroll
          for (int nt = 0; nt < 4; ++nt)
            accB[nt] = MFMA(af, bb[m & 3][nt], accB[nt]);
        }
        #pragma unroll
        for (int nt = 0; nt < 4; ++nt)
          #pragma unroll
          for (int r = 0; r < 4; ++r)
            *(unsigned short*)(h2f + hwaddr[nt] + (r << 4)) =
                f2b(fast_tanh(accB[nt][r] + b2v[nt]));
      }
      LBAR();   // h2 ready

      // ---- phase C: k = h2 @ w3.T + b3 + a @ A.T; stream iters 16..19 ---
      {
        f32x4 accC0 = {0.f, 0.f, 0.f, 0.f};
        f32x4 accC1 = {0.f, 0.f, 0.f, 0.f};
        #pragma unroll
        for (int cc = 0; cc < 4; ++cc) {
          LDGRP((19 + cc) & 3, 19 + cc);          // wraps into next stage
          __builtin_amdgcn_sched_barrier(0);
          bf16x8 a0 = *(const bf16x8*)(h2f + ((4*cc + 0) << 10) + lob);
          bf16x8 a1 = *(const bf16x8*)(h2f + ((4*cc + 1) << 10) + lob);
          bf16x8 a2 = *(const bf16x8*)(h2f + ((4*cc + 2) << 10) + lob);
          bf16x8 a3 = *(const bf16x8*)(h2f + ((4*cc + 3) << 10) + lob);
          accC0 = MFMA(a0, bb[cc][0], accC0);
          accC1 = MFMA(a1, bb[cc][1], accC1);
          accC0 = MFMA(a2, bb[cc][2], accC0);
          accC1 = MFMA(a3, bb[cc][3], accC1);
        }
        // A * y from resident Af
        #pragma unroll
        for (int kc = 0; kc < 4; ++kc) {
          bf16x8 afy = *(const bf16x8*)(ybr + (kc << 10) + lob);
          if (kc & 1) accC1 = MFMA(afy, Af[kc], accC1);
          else        accC0 = MFMA(afy, Af[kc], accC0);
        }
        float kk[4];
        #pragma unroll
        for (int r = 0; r < 4; ++r) kk[r] = accC0[r] + accC1[r] + b3v;
        switch (s) {
          case 0: CPK(k0); break;
          case 1: CPK(k1); break;
          case 2: CPK(k2); break;
          case 3: CPK(k3); break;
          case 4: CPK(k4); break;
          default: CPK(k5); break;
        }
      }

      // ---- phase D: RK combine in registers; write y-stage frags --------
      {
        const float* cp = (const float*)(smem_c + ATF + (s << 5));
        const float c0 = cp[0], c1 = cp[1], c2 = cp[2];
        const float c3 = cp[3], c4 = cp[4], c5 = cp[5];
        float a_[4];
        #pragma unroll
        for (int r = 0; r < 4; ++r)
          a_[r] = y[r] + hdt * (c0*k0[r] + c1*k1[r] + c2*k2[r] +
                                c3*k3[r] + c4*k4[r] + c5*k5[r]);
        #pragma unroll
        for (int r = 0; r < 4; ++r)
          *(unsigned short*)(ybw + ydst + (r << 4)) = f2b(a_[r]);
        if (s == 5) {
          #pragma unroll
          for (int r = 0; r < 4; ++r) {
            y[r] = a_[r];
            out[(size_t)(b0 + (quad << 2) + r) * (Tt * Dd) +
                (size_t)(t + 1) * Dd + nC] = a_[r];
          }
        }
      }
    } // stages
  } // steps
}

extern "C" void kernel_launch(void* const* d_in, const int* in_sizes, int n_in,
                              void* d_out, int out_size, void* d_ws, size_t ws_size,
                              hipStream_t stream) {
  (void)in_sizes; (void)n_in; (void)out_size; (void)ws_size;

  const float* ts = (const float*)d_in[0];
  const float* yi = (const float*)d_in[1];
  const float* w1 = (const float*)d_in[2];
  const float* b1 = (const float*)d_in[3];
  const float* w2 = (const float*)d_in[4];
  const float* b2 = (const float*)d_in[5];
  const float* w3 = (const float*)d_in[6];
  const float* b3 = (const float*)d_in[7];
  const float* Am = (const float*)d_in[8];
  float* outp = (float*)d_out;
  unsigned short* wsb = (unsigned short*)d_ws;

  (void)hipFuncSetAttribute(reinterpret_cast<const void*>(ode_kernel),
                            hipFuncAttributeMaxDynamicSharedMemorySize,
                            SMEMB);

  prep_kernel<<<400, 256, 0, stream>>>(w1, w2, w3, Am, wsb);
  ode_kernel<<<dim3(NWG), dim3(NTHR), SMEMB, stream>>>(
      ts, yi, b1, b2, b3, outp, wsb);
}

// Round 7
// 42515.152 us; speedup vs baseline: 1.1132x; 1.1132x over previous
//
#include <hip/hip_runtime.h>
#include <stdint.h>

// ---------------------------------------------------------------------------
// StabilizedNeuralODE v8: direct L2->VGPR stream, arch-VGPR-forced.
//
// v5 (33.9 ms): glds -> LDS ring -> ds_read. Decomposition shows ~6-7 us of
// the 11.1 us/stage is LDS-port occupancy for the 800 KB/CU-stage weight
// round-trip (DMA write 128 B/clk + b128 read ~85 B/cyc).
// v7 (45.3 ms): direct-to-reg, but VGPR_Count=128 proves the compiler put
// the stream buffers in AGPRs (global_load can't target AGPR -> VGPR-temp
// copies re-serialized the stream).
// v8 = v7's idea with the AGPR failure mode removed:
//  - loads are inline-asm global_load_dwordx4 with "=&v" outputs: the
//    destinations are architecturally FORCED into arch VGPRs.
//  - NO w1/A residency (that was the pressure that overflowed to AGPRs).
//    Total arch demand ~200 < 256 at 2 waves/SIMD.
//  - bb[5] buffers (80 VGPRs), issue distance 4 iters, consume distance 0;
//    25 iters/stage % 5 == 0 -> all indices compile-time, stream crosses
//    stage barriers seamlessly (v5's exact 50-group schedule and layout).
//  - per iter: s_waitcnt vmcnt(12) + sched_barrier(0) (in-order queue holds
//    <=16 loads (+4 transient s=5 out-stores, <=20); completing to 12 always
//    retires the iteration's 4 loads - stores only cause early completion).
//  - LDS carries activations only (h1/h2/y frags + tables, 43 KB); barriers
//    are raw s_barrier + lgkmcnt(0); vmcnt never drained inside the loop.
//
// Structure: 32 WGs x 512 threads (8 waves, 2/SIMD); WG owns 16 batch rows.
// MFMA 16x16x32_bf16 (verified): A-frag A[m=l16][k=quad*8+j],
// B-frag B[n=l16][k=quad*8+j], C/D n=l16, m=quad*4+reg.
// ---------------------------------------------------------------------------

#define Dd 128
#define Ww 512
#define Tt 512
#define NSTEP 511
#define NWG 32
#define NTHR 512

// workspace: per-wave consumption-order bf16 stream (v5 layout, verified)
#define GRP_USH 1024
#define WAVE_USH (50 * GRP_USH)
#define WS_TOT (8 * WAVE_USH)       // 819,200 bytes

// LDS byte offsets (activations only)
#define H1F 0                   // 16 x 512 bf16, fragment order (16 KB)
#define H2F 16384
#define Y0F 32768               // 16 x 128 bf16 frags (4 KB)
#define Y1F 36864
#define ATF 40960               // 6 x 8 f32 RK rows (192 B)
#define DTF 41152               // 511 f32 dt values
#define SMEMB 43200

typedef __attribute__((ext_vector_type(8))) __bf16 bf16x8;
typedef __attribute__((ext_vector_type(4))) float f32x4;

__device__ __forceinline__ unsigned short f2b(float f) {
  union { float f; unsigned int u; } v; v.f = f;
  return (unsigned short)((v.u + 0x7fffu + ((v.u >> 16) & 1u)) >> 16);
}
__device__ __forceinline__ float fast_tanh(float x) {
  x = fminf(fmaxf(x, -15.f), 15.f);
  float e = __expf(2.f * x);
  return (e - 1.f) / (e + 1.f);
}
// frag byte address of element (m=batch row 0..15, n=feature col):
// tile n>>5 (1 KB), lane ((n>>3)&3)*16+m (16 B), elem n&7.
__device__ __forceinline__ int fragaddr(int m, int n) {
  return ((n >> 5) << 10) + ((((n >> 3) & 3) * 16 + m) << 4) + ((n & 7) << 1);
}

// RK coefficients: rows 0..4 = A(s+1,*) zero-padded to 8, row 5 = B.
__device__ const float RKC[48] = {
  0.161f, 0.f, 0.f, 0.f, 0.f, 0.f, 0.f, 0.f,
  -0.008480655492356989f, 0.335480655492357f, 0.f, 0.f, 0.f, 0.f, 0.f, 0.f,
  2.8971530571054935f, -6.359448489975075f, 4.3622954328695815f, 0.f, 0.f, 0.f, 0.f, 0.f,
  5.325864828439257f, -11.748883564062828f, 7.4955393428898365f,
  -0.09249506636175525f, 0.f, 0.f, 0.f, 0.f,
  5.86145544294642f, -12.92096931784711f, 8.159367898576159f,
  -0.071584973281401f, -0.028269050394068383f, 0.f, 0.f, 0.f,
  0.09646076681806523f, 0.01f, 0.4798896504144996f, 1.379008574103742f,
  -3.290069515436081f, 2.324710524099774f, 0.f, 0.f
};

// one inline-asm load: 16 B/lane, destination FORCED to arch VGPRs ("v").
// gsb must be in scope at expansion site (per-lane stream base).
#define LDG1(dst, off_) \
  asm volatile("global_load_dwordx4 %0, %1, off" \
               : "=&v"(dst) : "v"(gsb + (off_)))

// issue one logical iteration's 4 KB (source iter mm of the 25/stage wrap)
#define ISSUE_ITER(bi, mm) do { \
    LDG1(bb[bi][0], (((mm) % 25) * 4096)); \
    LDG1(bb[bi][1], (((mm) % 25) * 4096 + 1024)); \
    LDG1(bb[bi][2], (((mm) % 25) * 4096 + 2048)); \
    LDG1(bb[bi][3], (((mm) % 25) * 4096 + 3072)); } while (0)

// counted wait: in-order queue <=16 loads (+4 transient stores); completing
// to 12 always retires the current iteration's loads. Never vmcnt(0) in-loop.
#define VMW12() do { asm volatile("s_waitcnt vmcnt(12)" ::: "memory"); \
                     __builtin_amdgcn_sched_barrier(0); } while (0)
// barrier that does NOT drain vmcnt
#define LBAR() do { asm volatile("s_waitcnt lgkmcnt(0)" ::: "memory"); \
                    __builtin_amdgcn_s_barrier(); } while (0)

#define MFMA(a, b, c) __builtin_amdgcn_mfma_f32_16x16x32_bf16((a), (b), (c), 0, 0, 0)
#define CPK(kd) do { kd[0]=kk[0]; kd[1]=kk[1]; kd[2]=kk[2]; kd[3]=kk[3]; } while (0)

// one-time permute+convert: per-wave fragment-order bf16 stream (v5 verbatim)
// group g: 0..7 w1 (nt=(g&1)*2+tile, ks=g>>1); 8..39 w2; 40..47 w3; 48..49 A
__global__ void prep_kernel(const float* __restrict__ w1,
                            const float* __restrict__ w2,
                            const float* __restrict__ w3,
                            const float* __restrict__ Am,
                            unsigned short* __restrict__ wsb) {
  for (int i = blockIdx.x * blockDim.x + threadIdx.x; i < WS_TOT;
       i += gridDim.x * blockDim.x) {
    const int j    = i & 7;
    const int L    = (i >> 3) & 63;
    const int l16  = L & 15;
    const int q    = L >> 4;
    const int tile = (i >> 9) & 1;
    const int g    = (i >> 10) % 50;
    const int w    = i / WAVE_USH;
    float v;
    if (g < 8) {
      const int nt = (g & 1) * 2 + tile, ks = g >> 1;
      v = w1[(w * 64 + nt * 16 + l16) * Dd + ks * 32 + q * 8 + j];
    } else if (g < 40) {
      const int gg = g - 8;
      const int nt = (gg & 1) * 2 + tile, ks = gg >> 1;
      v = w2[(w * 64 + nt * 16 + l16) * Ww + ks * 32 + q * 8 + j];
    } else if (g < 48) {
      const int kcol = 2 * (g - 40) + tile;
      v = w3[(w * 16 + l16) * Ww + kcol * 32 + q * 8 + j];
    } else {
      const int kcol = 2 * (g - 48) + tile;
      v = Am[(w * 16 + l16) * Dd + kcol * 32 + q * 8 + j];
    }
    wsb[i] = f2b(v);
  }
}

__global__ void __launch_bounds__(NTHR, 1)
ode_kernel(const float* __restrict__ ts,
           const float* __restrict__ yi,
           const float* __restrict__ b1,
           const float* __restrict__ b2,
           const float* __restrict__ b3,
           float* __restrict__ out,
           const unsigned short* __restrict__ wsb)
{
  extern __shared__ char smem_c[];

  const int tid  = threadIdx.x;
  const int wid  = tid >> 6;
  const int lane = tid & 63;
  const int l16  = lane & 15;
  const int quad = lane >> 4;
  const int lob  = lane << 4;          // lane*16 bytes
  const int b0   = blockIdx.x * 16;

  char* h1f = smem_c + H1F;
  char* h2f = smem_c + H2F;

  // per-lane stream base: wave slice + lane*16 (fully coalesced)
  const char* gsb = (const char*)(wsb + wid * WAVE_USH) + lob;

  // ---- one-time staging: RK table + dt into LDS; biases into regs ----
  if (tid < 48) *(float*)(smem_c + ATF + (tid << 2)) = RKC[tid];
  for (int i = tid; i < NSTEP; i += NTHR)
    *(float*)(smem_c + DTF + (i << 2)) = ts[i + 1] - ts[i];

  float b1v[4], b2v[4];
  #pragma unroll
  for (int nt = 0; nt < 4; ++nt) {
    b1v[nt] = b1[(wid << 6) + (nt << 4) + l16];
    b2v[nt] = b2[(wid << 6) + (nt << 4) + l16];
  }
  const float b3v = b3[(wid << 4) + l16];

  // h-frag write bases: n = wid*64+nt*16+l16, m = quad*4 (+r = r*16 B)
  int hwaddr[4];
  #pragma unroll
  for (int nt = 0; nt < 4; ++nt)
    hwaddr[nt] = fragaddr(quad << 2, (wid << 6) + (nt << 4) + l16);
  const int nC = (wid << 4) + l16;          // phase C/D column
  const int ydst = fragaddr(quad << 2, nC); // y-frag write base

  // ---- y0: 4 fp32 regs (rows quad*4+r, col nC), Y0F frags, out[t=0] ----
  float y[4];
  #pragma unroll
  for (int r = 0; r < 4; ++r) {
    y[r] = yi[(size_t)(b0 + (quad << 2) + r) * Dd + nC];
    *(unsigned short*)(smem_c + Y0F + ydst + (r << 4)) = f2b(y[r]);
    out[(size_t)(b0 + (quad << 2) + r) * (Tt * Dd) + nC] = y[r];
  }

  float k0[4] = {0,0,0,0}, k1[4] = {0,0,0,0}, k2[4] = {0,0,0,0},
        k3[4] = {0,0,0,0}, k4[4] = {0,0,0,0}, k5[4] = {0,0,0,0};

  __syncthreads();   // init visible; vmcnt drained to 0 here

  // stream buffers (arch VGPRs, 80 regs); prologue: iters 0..3 in flight
  bf16x8 bb[5][4];
  ISSUE_ITER(0, 0); ISSUE_ITER(1, 1); ISSUE_ITER(2, 2); ISSUE_ITER(3, 3);

  #pragma unroll 1
  for (int t = 0; t < NSTEP; ++t) {
    const float hdt = *(const float*)(smem_c + DTF + (t << 2));

    #pragma unroll 1
    for (int s = 0; s < 6; ++s) {
      const char* ybr = smem_c + ((s & 1) ? Y1F : Y0F);
      char*       ybw = smem_c + ((s & 1) ? Y0F : Y1F);

      LBAR();   // y(parity) ready; h buffers free

      // ---- phase A: h1 = tanh(a @ w1.T + b1); stream iters 0..3 ---------
      {
        f32x4 accA[4];
        #pragma unroll
        for (int nt = 0; nt < 4; ++nt) { f32x4 z = {0.f,0.f,0.f,0.f}; accA[nt] = z; }
        #pragma unroll
        for (int m = 0; m < 4; ++m) {
          VMW12();
          bf16x8 af = *(const bf16x8*)(ybr + (m << 10) + lob);
          ISSUE_ITER((m + 4) % 5, m + 4);
          #pragma unroll
          for (int nt = 0; nt < 4; ++nt)
            accA[nt] = MFMA(af, bb[m][nt], accA[nt]);
        }
        #pragma unroll
        for (int nt = 0; nt < 4; ++nt)
          #pragma unroll
          for (int r = 0; r < 4; ++r)
            *(unsigned short*)(h1f + hwaddr[nt] + (r << 4)) =
                f2b(fast_tanh(accA[nt][r] + b1v[nt]));
      }
      LBAR();   // h1 ready

      // ---- phase B: h2 = tanh(h1 @ w2.T + b2); stream iters 4..19 -------
      {
        f32x4 accB[4];
        #pragma unroll
        for (int nt = 0; nt < 4; ++nt) { f32x4 z = {0.f,0.f,0.f,0.f}; accB[nt] = z; }
        #pragma unroll
        for (int ks = 0; ks < 16; ++ks) {
          VMW12();
          bf16x8 af = *(const bf16x8*)(h1f + (ks << 10) + lob);
          ISSUE_ITER((ks + 8) % 5, ks + 8);
          #pragma unroll
          for (int nt = 0; nt < 4; ++nt)
            accB[nt] = MFMA(af, bb[(ks + 4) % 5][nt], accB[nt]);
        }
        #pragma unroll
        for (int nt = 0; nt < 4; ++nt)
          #pragma unroll
          for (int r = 0; r < 4; ++r)
            *(unsigned short*)(h2f + hwaddr[nt] + (r << 4)) =
                f2b(fast_tanh(accB[nt][r] + b2v[nt]));
      }
      LBAR();   // h2 ready

      // ---- phase C: k = h2 @ w3.T + b3 + a @ A.T; stream iters 20..24 ---
      {
        f32x4 accC0 = {0.f, 0.f, 0.f, 0.f};
        f32x4 accC1 = {0.f, 0.f, 0.f, 0.f};
        #pragma unroll
        for (int cc = 0; cc < 5; ++cc) {
          VMW12();
          bf16x8 a0, a1, a2, a3;
          if (cc < 4) {
            a0 = *(const bf16x8*)(h2f + ((4*cc + 0) << 10) + lob);
            a1 = *(const bf16x8*)(h2f + ((4*cc + 1) << 10) + lob);
            a2 = *(const bf16x8*)(h2f + ((4*cc + 2) << 10) + lob);
            a3 = *(const bf16x8*)(h2f + ((4*cc + 3) << 10) + lob);
          } else {
            a0 = *(const bf16x8*)(ybr + (0 << 10) + lob);
            a1 = *(const bf16x8*)(ybr + (1 << 10) + lob);
            a2 = *(const bf16x8*)(ybr + (2 << 10) + lob);
            a3 = *(const bf16x8*)(ybr + (3 << 10) + lob);
          }
          ISSUE_ITER((cc + 24) % 5, cc + 24);   // cc=0 -> iter 24; cc>=1 -> next stage
          accC0 = MFMA(a0, bb[cc][0], accC0);
          accC1 = MFMA(a1, bb[cc][1], accC1);
          accC0 = MFMA(a2, bb[cc][2], accC0);
          accC1 = MFMA(a3, bb[cc][3], accC1);
        }
        float kk[4];
        #pragma unroll
        for (int r = 0; r < 4; ++r) kk[r] = accC0[r] + accC1[r] + b3v;
        switch (s) {
          case 0: CPK(k0); break;
          case 1: CPK(k1); break;
          case 2: CPK(k2); break;
          case 3: CPK(k3); break;
          case 4: CPK(k4); break;
          default: CPK(k5); break;
        }
      }

      // ---- phase D: RK combine in registers; write y-stage frags --------
      {
        const float* cp = (const float*)(smem_c + ATF + (s << 5));
        const float c0 = cp[0], c1 = cp[1], c2 = cp[2];
        const float c3 = cp[3], c4 = cp[4], c5 = cp[5];
        float a_[4];
        #pragma unroll
        for (int r = 0; r < 4; ++r)
          a_[r] = y[r] + hdt * (c0*k0[r] + c1*k1[r] + c2*k2[r] +
                                c3*k3[r] + c4*k4[r] + c5*k5[r]);
        #pragma unroll
        for (int r = 0; r < 4; ++r)
          *(unsigned short*)(ybw + ydst + (r << 4)) = f2b(a_[r]);
        if (s == 5) {
          #pragma unroll
          for (int r = 0; r < 4; ++r) {
            y[r] = a_[r];
            out[(size_t)(b0 + (quad << 2) + r) * (Tt * Dd) +
                (size_t)(t + 1) * Dd + nC] = a_[r];
          }
        }
      }
    } // stages
  } // steps

  // drain the tail prefetches before wave end
  asm volatile("s_waitcnt vmcnt(0) lgkmcnt(0)" ::: "memory");
}

extern "C" void kernel_launch(void* const* d_in, const int* in_sizes, int n_in,
                              void* d_out, int out_size, void* d_ws, size_t ws_size,
                              hipStream_t stream) {
  (void)in_sizes; (void)n_in; (void)out_size; (void)ws_size;

  const float* ts = (const float*)d_in[0];
  const float* yi = (const float*)d_in[1];
  const float* w1 = (const float*)d_in[2];
  const float* b1 = (const float*)d_in[3];
  const float* w2 = (const float*)d_in[4];
  const float* b2 = (const float*)d_in[5];
  const float* w3 = (const float*)d_in[6];
  const float* b3 = (const float*)d_in[7];
  const float* Am = (const float*)d_in[8];
  float* outp = (float*)d_out;
  unsigned short* wsb = (unsigned short*)d_ws;

  (void)hipFuncSetAttribute(reinterpret_cast<const void*>(ode_kernel),
                            hipFuncAttributeMaxDynamicSharedMemorySize,
                            SMEMB);

  prep_kernel<<<400, 256, 0, stream>>>(w1, w2, w3, Am, wsb);
  ode_kernel<<<dim3(NWG), dim3(NTHR), SMEMB, stream>>>(
      ts, yi, b1, b2, b3, outp, wsb);
}

// Round 8
// 35195.468 us; speedup vs baseline: 1.3447x; 1.2080x over previous
//
#include <hip/hip_runtime.h>
#include <stdint.h>

// ---------------------------------------------------------------------------
// StabilizedNeuralODE v9: hybrid weight stream — glds/LDS ring (nt 0,1)
// CONCURRENT with direct L2->VGPR loads (nt 2,3).
//
// Evidence: v5 (33.9 ms) is LDS-port-bound (weights round-trip LDS: ~20k
// cyc/stage/CU); v8 (42.5 ms) is VMEM-return-bound (~60 GB/s/CU). The two
// paths use different ports and can overlap. v9 splits each 4 KB iteration:
//   2 KB -> glds ring (v5's verified 5-slot/wave ring, depth 3)
//   2 KB -> inline-asm global_load_dwordx4 into arch VGPRs (v8's verified
//           "=&v" mechanism), buffers bbd[5][2], depth 3
// Both counted by one vmcnt: 4 ops/iter batches, s_waitcnt vmcnt(8) retires
// the oldest batch (intra-batch order irrelevant; batches can't interleave
// across sched_barrier(0) fences). Ring slot reuse distance 5 > depth 3.
// 25 iters/stage, 25%5==0 -> all indices compile-time across stages.
//
// Structure: 32 WGs x 512 threads (8 waves, 2/SIMD); WG owns 16 batch rows.
// prep_kernel and consumption math identical to v5 (PASSED).
// Stream order per wave (1 KB tiles, consumption order):
//   iter m (0..24): tiles 4m..4m+3 = groups 2m (nt0,1), 2m+1 (nt2,3)
//   groups: 0..7 w1 | 8..39 w2 | 40..47 w3 | 48..49 A
// MFMA 16x16x32_bf16 (verified): A-frag A[m=l16][k=quad*8+j],
// B-frag B[n=l16][k=quad*8+j], C/D n=l16, m=quad*4+reg.
// ---------------------------------------------------------------------------

#define Dd 128
#define Ww 512
#define Tt 512
#define NSTEP 511
#define NWG 32
#define NTHR 512

// workspace: per-wave consumption-order bf16 stream (v5 layout, verified)
#define GRP_USH 1024
#define WAVE_USH (50 * GRP_USH)
#define WS_TOT (8 * WAVE_USH)       // 819,200 bytes

// LDS byte offsets
#define RING_PER_WAVE 10240   // 5 slots x 2048 B
#define H1F 81920             // 16 x 512 bf16, fragment order (16 KB)
#define H2F 98304
#define Y0F 114688            // 16 x 128 bf16 frags (4 KB)
#define Y1F 118784
#define ATF 122880            // 6 x 8 f32 RK rows (192 B)
#define DTF 123072            // 511 f32 dt values
#define SMEMB 125120

typedef __attribute__((ext_vector_type(8))) __bf16 bf16x8;
typedef __attribute__((ext_vector_type(4))) float f32x4;

__device__ __forceinline__ unsigned short f2b(float f) {
  union { float f; unsigned int u; } v; v.f = f;
  return (unsigned short)((v.u + 0x7fffu + ((v.u >> 16) & 1u)) >> 16);
}
__device__ __forceinline__ float fast_tanh(float x) {
  x = fminf(fmaxf(x, -15.f), 15.f);
  float e = __expf(2.f * x);
  return (e - 1.f) / (e + 1.f);
}
// frag byte address of element (m=batch row 0..15, n=feature col):
// tile n>>5 (1 KB), lane ((n>>3)&3)*16+m (16 B), elem n&7.
__device__ __forceinline__ int fragaddr(int m, int n) {
  return ((n >> 5) << 10) + ((((n >> 3) & 3) * 16 + m) << 4) + ((n & 7) << 1);
}

// RK coefficients: rows 0..4 = A(s+1,*) zero-padded to 8, row 5 = B.
__device__ const float RKC[48] = {
  0.161f, 0.f, 0.f, 0.f, 0.f, 0.f, 0.f, 0.f,
  -0.008480655492356989f, 0.335480655492357f, 0.f, 0.f, 0.f, 0.f, 0.f, 0.f,
  2.8971530571054935f, -6.359448489975075f, 4.3622954328695815f, 0.f, 0.f, 0.f, 0.f, 0.f,
  5.325864828439257f, -11.748883564062828f, 7.4955393428898365f,
  -0.09249506636175525f, 0.f, 0.f, 0.f, 0.f,
  5.86145544294642f, -12.92096931784711f, 8.159367898576159f,
  -0.071584973281401f, -0.028269050394068383f, 0.f, 0.f, 0.f,
  0.09646076681806523f, 0.01f, 0.4798896504144996f, 1.379008574103742f,
  -3.290069515436081f, 2.324710524099774f, 0.f, 0.f
};

#define GLDS(gp, lp) __builtin_amdgcn_global_load_lds( \
    (const __attribute__((address_space(1))) unsigned int*)(const void*)(gp), \
    (__attribute__((address_space(3))) unsigned int*)(void*)(lp), 16, 0, 0)

// direct load, destination FORCED to arch VGPRs (v8-verified mechanism)
#define LDG1(dst, off_) \
  asm volatile("global_load_dwordx4 %0, %1, off" \
               : "=&v"(dst) : "v"(gsbb + (off_)))

#define ITS(mm) (((mm) % 25) * 4096)
#define BI(mm) ((mm) % 5)
// issue one iteration batch: 2 glds (ring) + 2 direct loads (regs)
#define ISS(mm) do { \
    GLDS(gsbb + ITS(mm),        ring_w + BI(mm) * 2048); \
    GLDS(gsbb + ITS(mm) + 1024, ring_w + BI(mm) * 2048 + 1024); \
    LDG1(bbd[BI(mm)][0], ITS(mm) + 2048); \
    LDG1(bbd[BI(mm)][1], ITS(mm) + 3072); } while (0)

// counted wait: retires the oldest in-flight batch (4 ops), leaves 2
// batches (8 ops) in flight. Never vmcnt(0) inside the loop.
#define VMW8() do { asm volatile("s_waitcnt vmcnt(8)" ::: "memory"); \
                    __builtin_amdgcn_sched_barrier(0); } while (0)
// ring/activation data provably in VGPRs before the overwrite issue
#define LGKM0() do { asm volatile("s_waitcnt lgkmcnt(0)" ::: "memory"); \
                     __builtin_amdgcn_sched_barrier(0); } while (0)
// barrier that does NOT drain vmcnt
#define LBAR() do { asm volatile("s_waitcnt lgkmcnt(0)" ::: "memory"); \
                    __builtin_amdgcn_s_barrier(); } while (0)

#define MFMA(a, b, c) __builtin_amdgcn_mfma_f32_16x16x32_bf16((a), (b), (c), 0, 0, 0)
#define CPK(kd) do { kd[0]=kk[0]; kd[1]=kk[1]; kd[2]=kk[2]; kd[3]=kk[3]; } while (0)

// one-time permute+convert: per-wave fragment-order bf16 stream (v5 verbatim)
__global__ void prep_kernel(const float* __restrict__ w1,
                            const float* __restrict__ w2,
                            const float* __restrict__ w3,
                            const float* __restrict__ Am,
                            unsigned short* __restrict__ wsb) {
  for (int i = blockIdx.x * blockDim.x + threadIdx.x; i < WS_TOT;
       i += gridDim.x * blockDim.x) {
    const int j    = i & 7;
    const int L    = (i >> 3) & 63;
    const int l16  = L & 15;
    const int q    = L >> 4;
    const int tile = (i >> 9) & 1;
    const int g    = (i >> 10) % 50;
    const int w    = i / WAVE_USH;
    float v;
    if (g < 8) {
      const int nt = (g & 1) * 2 + tile, ks = g >> 1;
      v = w1[(w * 64 + nt * 16 + l16) * Dd + ks * 32 + q * 8 + j];
    } else if (g < 40) {
      const int gg = g - 8;
      const int nt = (gg & 1) * 2 + tile, ks = gg >> 1;
      v = w2[(w * 64 + nt * 16 + l16) * Ww + ks * 32 + q * 8 + j];
    } else if (g < 48) {
      const int kcol = 2 * (g - 40) + tile;
      v = w3[(w * 16 + l16) * Ww + kcol * 32 + q * 8 + j];
    } else {
      const int kcol = 2 * (g - 48) + tile;
      v = Am[(w * 16 + l16) * Dd + kcol * 32 + q * 8 + j];
    }
    wsb[i] = f2b(v);
  }
}

__global__ void __launch_bounds__(NTHR, 1)
ode_kernel(const float* __restrict__ ts,
           const float* __restrict__ yi,
           const float* __restrict__ b1,
           const float* __restrict__ b2,
           const float* __restrict__ b3,
           float* __restrict__ out,
           const unsigned short* __restrict__ wsb)
{
  extern __shared__ char smem_c[];

  const int tid  = threadIdx.x;
  const int wid  = tid >> 6;
  const int lane = tid & 63;
  const int l16  = lane & 15;
  const int quad = lane >> 4;
  const int lob  = lane << 4;          // lane*16 bytes
  const int b0   = blockIdx.x * 16;

  char* ring_w = smem_c + wid * RING_PER_WAVE;
  char* h1f = smem_c + H1F;
  char* h2f = smem_c + H2F;

  // per-lane stream base (wave slice + lane*16) for BOTH glds and direct
  const char* gsbb = (const char*)(wsb + wid * WAVE_USH) + lob;

  // ---- one-time staging: RK table + dt into LDS; biases into regs ----
  if (tid < 48) *(float*)(smem_c + ATF + (tid << 2)) = RKC[tid];
  for (int i = tid; i < NSTEP; i += NTHR)
    *(float*)(smem_c + DTF + (i << 2)) = ts[i + 1] - ts[i];

  float b1v[4], b2v[4];
  #pragma unroll
  for (int nt = 0; nt < 4; ++nt) {
    b1v[nt] = b1[(wid << 6) + (nt << 4) + l16];
    b2v[nt] = b2[(wid << 6) + (nt << 4) + l16];
  }
  const float b3v = b3[(wid << 4) + l16];

  // h-frag write bases: n = wid*64+nt*16+l16, m = quad*4 (+r = r*16 B)
  int hwaddr[4];
  #pragma unroll
  for (int nt = 0; nt < 4; ++nt)
    hwaddr[nt] = fragaddr(quad << 2, (wid << 6) + (nt << 4) + l16);
  const int nC = (wid << 4) + l16;          // phase C/D column
  const int ydst = fragaddr(quad << 2, nC); // y-frag write base

  // ---- y0: 4 fp32 regs (rows quad*4+r, col nC), Y0F frags, out[t=0] ----
  float y[4];
  #pragma unroll
  for (int r = 0; r < 4; ++r) {
    y[r] = yi[(size_t)(b0 + (quad << 2) + r) * Dd + nC];
    *(unsigned short*)(smem_c + Y0F + ydst + (r << 4)) = f2b(y[r]);
    out[(size_t)(b0 + (quad << 2) + r) * (Tt * Dd) + nC] = y[r];
  }

  float k0[4] = {0,0,0,0}, k1[4] = {0,0,0,0}, k2[4] = {0,0,0,0},
        k3[4] = {0,0,0,0}, k4[4] = {0,0,0,0}, k5[4] = {0,0,0,0};

  __syncthreads();   // init visible; vmcnt drained to 0 here

  // direct-path register buffers (arch VGPRs, 40 regs)
  bf16x8 bbd[5][2];
  // prologue: batches 0..2 in flight (12 ops)
  ISS(0); ISS(1); ISS(2);

  #pragma unroll 1
  for (int t = 0; t < NSTEP; ++t) {
    const float hdt = *(const float*)(smem_c + DTF + (t << 2));

    #pragma unroll 1
    for (int s = 0; s < 6; ++s) {
      const char* ybr = smem_c + ((s & 1) ? Y1F : Y0F);
      char*       ybw = smem_c + ((s & 1) ? Y0F : Y1F);

      LBAR();   // y(parity) ready; h buffers free

      // ---- phase A: h1 = tanh(a @ w1.T + b1); iters 0..3 ----------------
      {
        f32x4 accA[4];
        #pragma unroll
        for (int nt = 0; nt < 4; ++nt) { f32x4 z = {0.f,0.f,0.f,0.f}; accA[nt] = z; }
        #pragma unroll
        for (int m = 0; m < 4; ++m) {
          VMW8();
          bf16x8 af  = *(const bf16x8*)(ybr + (m << 10) + lob);
          bf16x8 bv0 = *(const bf16x8*)(ring_w + BI(m) * 2048 + lob);
          bf16x8 bv1 = *(const bf16x8*)(ring_w + BI(m) * 2048 + 1024 + lob);
          LGKM0();
          ISS(m + 3);
          accA[0] = MFMA(af, bv0, accA[0]);
          accA[1] = MFMA(af, bv1, accA[1]);
          accA[2] = MFMA(af, bbd[BI(m)][0], accA[2]);
          accA[3] = MFMA(af, bbd[BI(m)][1], accA[3]);
        }
        #pragma unroll
        for (int nt = 0; nt < 4; ++nt)
          #pragma unroll
          for (int r = 0; r < 4; ++r)
            *(unsigned short*)(h1f + hwaddr[nt] + (r << 4)) =
                f2b(fast_tanh(accA[nt][r] + b1v[nt]));
      }
      LBAR();   // h1 ready

      // ---- phase B: h2 = tanh(h1 @ w2.T + b2); iters 4..19 --------------
      {
        f32x4 accB[4];
        #pragma unroll
        for (int nt = 0; nt < 4; ++nt) { f32x4 z = {0.f,0.f,0.f,0.f}; accB[nt] = z; }
        #pragma unroll
        for (int ks = 0; ks < 16; ++ks) {
          const int m = 4 + ks;
          VMW8();
          bf16x8 af  = *(const bf16x8*)(h1f + (ks << 10) + lob);
          bf16x8 bv0 = *(const bf16x8*)(ring_w + BI(m) * 2048 + lob);
          bf16x8 bv1 = *(const bf16x8*)(ring_w + BI(m) * 2048 + 1024 + lob);
          LGKM0();
          ISS(m + 3);
          accB[0] = MFMA(af, bv0, accB[0]);
          accB[1] = MFMA(af, bv1, accB[1]);
          accB[2] = MFMA(af, bbd[BI(m)][0], accB[2]);
          accB[3] = MFMA(af, bbd[BI(m)][1], accB[3]);
        }
        #pragma unroll
        for (int nt = 0; nt < 4; ++nt)
          #pragma unroll
          for (int r = 0; r < 4; ++r)
            *(unsigned short*)(h2f + hwaddr[nt] + (r << 4)) =
                f2b(fast_tanh(accB[nt][r] + b2v[nt]));
      }
      LBAR();   // h2 ready

      // ---- phase C: k = h2 @ w3.T + b3 + a @ A.T; iters 20..24 ----------
      {
        f32x4 accC0 = {0.f, 0.f, 0.f, 0.f};
        f32x4 accC1 = {0.f, 0.f, 0.f, 0.f};
        #pragma unroll
        for (int cc = 0; cc < 5; ++cc) {
          const int m = 20 + cc;
          VMW8();
          bf16x8 a0, a1, a2, a3;
          if (cc < 4) {
            a0 = *(const bf16x8*)(h2f + ((4*cc + 0) << 10) + lob);
            a1 = *(const bf16x8*)(h2f + ((4*cc + 1) << 10) + lob);
            a2 = *(const bf16x8*)(h2f + ((4*cc + 2) << 10) + lob);
            a3 = *(const bf16x8*)(h2f + ((4*cc + 3) << 10) + lob);
          } else {
            a0 = *(const bf16x8*)(ybr + (0 << 10) + lob);
            a1 = *(const bf16x8*)(ybr + (1 << 10) + lob);
            a2 = *(const bf16x8*)(ybr + (2 << 10) + lob);
            a3 = *(const bf16x8*)(ybr + (3 << 10) + lob);
          }
          bf16x8 bv0 = *(const bf16x8*)(ring_w + BI(m) * 2048 + lob);
          bf16x8 bv1 = *(const bf16x8*)(ring_w + BI(m) * 2048 + 1024 + lob);
          LGKM0();
          ISS(m + 3);   // cc>=2 wraps into next stage (mod 25)
          accC0 = MFMA(a0, bv0, accC0);
          accC1 = MFMA(a1, bv1, accC1);
          accC0 = MFMA(a2, bbd[BI(m)][0], accC0);
          accC1 = MFMA(a3, bbd[BI(m)][1], accC1);
        }
        float kk[4];
        #pragma unroll
        for (int r = 0; r < 4; ++r) kk[r] = accC0[r] + accC1[r] + b3v;
        switch (s) {
          case 0: CPK(k0); break;
          case 1: CPK(k1); break;
          case 2: CPK(k2); break;
          case 3: CPK(k3); break;
          case 4: CPK(k4); break;
          default: CPK(k5); break;
        }
      }

      // ---- phase D: RK combine in registers; write y-stage frags --------
      {
        const float* cp = (const float*)(smem_c + ATF + (s << 5));
        const float c0 = cp[0], c1 = cp[1], c2 = cp[2];
        const float c3 = cp[3], c4 = cp[4], c5 = cp[5];
        float a_[4];
        #pragma unroll
        for (int r = 0; r < 4; ++r)
          a_[r] = y[r] + hdt * (c0*k0[r] + c1*k1[r] + c2*k2[r] +
                                c3*k3[r] + c4*k4[r] + c5*k5[r]);
        #pragma unroll
        for (int r = 0; r < 4; ++r)
          *(unsigned short*)(ybw + ydst + (r << 4)) = f2b(a_[r]);
        if (s == 5) {
          #pragma unroll
          for (int r = 0; r < 4; ++r) {
            y[r] = a_[r];
            out[(size_t)(b0 + (quad << 2) + r) * (Tt * Dd) +
                (size_t)(t + 1) * Dd + nC] = a_[r];
          }
        }
      }
    } // stages
  } // steps

  // drain tail prefetches before wave end
  asm volatile("s_waitcnt vmcnt(0) lgkmcnt(0)" ::: "memory");
}

extern "C" void kernel_launch(void* const* d_in, const int* in_sizes, int n_in,
                              void* d_out, int out_size, void* d_ws, size_t ws_size,
                              hipStream_t stream) {
  (void)in_sizes; (void)n_in; (void)out_size; (void)ws_size;

  const float* ts = (const float*)d_in[0];
  const float* yi = (const float*)d_in[1];
  const float* w1 = (const float*)d_in[2];
  const float* b1 = (const float*)d_in[3];
  const float* w2 = (const float*)d_in[4];
  const float* b2 = (const float*)d_in[5];
  const float* w3 = (const float*)d_in[6];
  const float* b3 = (const float*)d_in[7];
  const float* Am = (const float*)d_in[8];
  float* outp = (float*)d_out;
  unsigned short* wsb = (unsigned short*)d_ws;

  (void)hipFuncSetAttribute(reinterpret_cast<const void*>(ode_kernel),
                            hipFuncAttributeMaxDynamicSharedMemorySize,
                            SMEMB);

  prep_kernel<<<400, 256, 0, stream>>>(w1, w2, w3, Am, wsb);
  ode_kernel<<<dim3(NWG), dim3(NTHR), SMEMB, stream>>>(
      ts, yi, b1, b2, b3, outp, wsb);
}